// Round 6
// baseline (452.188 us; speedup 1.0000x reference)
//
#include <hip/hip_runtime.h>

#define B_    4
#define N_    512
#define IND_  300
#define H_    128
#define QQ    8          // queries per attention block
#define KC    16         // k-chunks; KC blocks fan-in per (b,qg) group
#define RR    4          // rows per prep block
#define LOG2E 1.4426950408889634f

typedef float v2f __attribute__((ext_vector_type(2)));

// ---------------------------------------------------------------------------
// Packing: transpose weights to [i/4][t][4] float4 tiles (coalesced dwordx4
// in prep). Wa/Ua pre-scaled by log2e. Block 0 also zeroes the fan-in
// counters (this dispatch precedes attn on the stream).
// ---------------------------------------------------------------------------
__global__ void pack_all(const float* __restrict__ Wx_w,
                         const float* __restrict__ Wa_w,
                         const float* __restrict__ Ua_w,
                         float* __restrict__ WxT4,
                         float* __restrict__ WaT4,
                         float* __restrict__ UaT4,
                         unsigned int* __restrict__ cnt) {
    const int blk = blockIdx.x;
    const int t   = threadIdx.x;
    if (blk == 0) {                       // zero 256 group counters
        cnt[t] = 0u;
        cnt[t + 128] = 0u;
    }
    if (blk < IND_) {
        const int i = blk;
        WxT4[(i >> 2) * 512 + t * 4 + (i & 3)] = Wx_w[t * IND_ + i];
    } else if (blk < IND_ + H_) {
        const int i = blk - IND_;
        WaT4[(i >> 2) * 512 + t * 4 + (i & 3)] = Wa_w[t * H_ + i] * LOG2E;
    } else {
        const int i = blk - IND_ - H_;
        UaT4[(i >> 2) * 512 + t * 4 + (i & 3)] = Ua_w[t * H_ + i] * LOG2E;
    }
}

// ---------------------------------------------------------------------------
// Prep, RR rows per block: h = tanh(x.Wx^T + bx)
//   Eta = exp(h.Wa^T + ba)                         [B*N, H]
//   kv  = {Et=exp(h.Ua^T+bu), M=exp(mask), M*h, 0} [B*N, H]
// ---------------------------------------------------------------------------
__global__ __launch_bounds__(128) void prep4(
    const float* __restrict__ x,      // [B*N, IND]
    const float* __restrict__ WxT4,   // [75][128][4]
    const float* __restrict__ Wx_b,
    const float* __restrict__ WaT4,   // [32][128][4], pre-scaled log2e
    const float* __restrict__ Wa_b,
    const float* __restrict__ UaT4,   // [32][128][4], pre-scaled log2e
    const float* __restrict__ Ua_b,
    const float* __restrict__ mask,   // [B*N, H]
    float* __restrict__ Eta,          // [B*N, H]
    float4* __restrict__ kv)          // [B*N, H]
{
    __shared__ __align__(16) float xs[RR * IND_];
    __shared__ __align__(16) float hs[RR][H_];

    const int r0 = blockIdx.x * RR;
    const int t  = threadIdx.x;

    const float4* xg = (const float4*)(x + (size_t)r0 * IND_);
    float4* xs4 = (float4*)xs;
    #pragma unroll
    for (int i = t; i < RR * IND_ / 4; i += 128) xs4[i] = xg[i];
    __syncthreads();

    float acc[RR];
    {
        const float bx = Wx_b[t];
        #pragma unroll
        for (int r = 0; r < RR; ++r) acc[r] = bx;
    }
    const float4* w4 = (const float4*)WxT4 + t;
    #pragma unroll 5
    for (int i4 = 0; i4 < IND_ / 4; ++i4) {
        float4 w = w4[i4 * 128];
        #pragma unroll
        for (int r = 0; r < RR; ++r) {
            float4 xv = *(const float4*)(xs + r * IND_ + 4 * i4);
            acc[r] = fmaf(w.x, xv.x, acc[r]);
            acc[r] = fmaf(w.y, xv.y, acc[r]);
            acc[r] = fmaf(w.z, xv.z, acc[r]);
            acc[r] = fmaf(w.w, xv.w, acc[r]);
        }
    }
    #pragma unroll
    for (int r = 0; r < RR; ++r) hs[r][t] = tanhf(acc[r]);
    __syncthreads();

    float accA[RR], accU[RR];
    {
        const float ba = Wa_b[t] * LOG2E;
        const float bu = Ua_b[t] * LOG2E;
        #pragma unroll
        for (int r = 0; r < RR; ++r) { accA[r] = ba; accU[r] = bu; }
    }
    const float4* wa4 = (const float4*)WaT4 + t;
    const float4* ua4 = (const float4*)UaT4 + t;
    #pragma unroll 4
    for (int i4 = 0; i4 < H_ / 4; ++i4) {
        float4 wa = wa4[i4 * 128];
        float4 ua = ua4[i4 * 128];
        #pragma unroll
        for (int r = 0; r < RR; ++r) {
            float4 hv = *(const float4*)(&hs[r][4 * i4]);
            accA[r] = fmaf(wa.x, hv.x, accA[r]);
            accA[r] = fmaf(wa.y, hv.y, accA[r]);
            accA[r] = fmaf(wa.z, hv.z, accA[r]);
            accA[r] = fmaf(wa.w, hv.w, accA[r]);
            accU[r] = fmaf(ua.x, hv.x, accU[r]);
            accU[r] = fmaf(ua.y, hv.y, accU[r]);
            accU[r] = fmaf(ua.z, hv.z, accU[r]);
            accU[r] = fmaf(ua.w, hv.w, accU[r]);
        }
    }
    #pragma unroll
    for (int r = 0; r < RR; ++r) {
        const size_t o = (size_t)(r0 + r) * H_ + t;
        Eta[o]  = __builtin_amdgcn_exp2f(accA[r]);
        float M = __builtin_amdgcn_exp2f(mask[o] * LOG2E);
        float h = hs[r][t];
        kv[o]   = make_float4(__builtin_amdgcn_exp2f(accU[r]), M, M * h, 0.f);
    }
}

// ---------------------------------------------------------------------------
// Attention + fan-in finalize. Per score: e = Eta*Et; p0 = (e>1)?e:exp(e-1);
// l += p0*M; c += p0*Mh. e/arg packed across adjacent q (v_pk_mul/fma),
// {l,c} packed per score -> ~5 issue slots/score.
// Last block of each (b,qg) group (via device-scope counter) sums the KC
// partial slices and writes out = c/l.
// ---------------------------------------------------------------------------
__global__ __launch_bounds__(128) void attn5(
    const float* __restrict__ Eta,    // [B*N, H]
    const float4* __restrict__ kv,    // [B*N, H] {Et, M, Mh, 0}
    float2* __restrict__ accum,       // [KC, B*N, H] {l, c}
    unsigned int* __restrict__ cnt,   // [256] fan-in counters
    float* __restrict__ out)          // [B*N, H]
{
    const int c  = blockIdx.x;        // 0..KC-1
    const int qg = blockIdx.y;        // 0..N/QQ-1
    const int b  = blockIdx.z;        // 0..B-1
    const int t  = threadIdx.x;
    const int q0 = qg * QQ;
    const int k0 = c * (N_ / KC);

    v2f eta2[QQ / 2];
    v2f lc[QQ];                       // {l, c} per q
    #pragma unroll
    for (int j = 0; j < QQ / 2; ++j) {
        eta2[j].x = Eta[((size_t)(b * N_ + q0 + 2 * j)) * H_ + t];
        eta2[j].y = Eta[((size_t)(b * N_ + q0 + 2 * j + 1)) * H_ + t];
    }
    #pragma unroll
    for (int j = 0; j < QQ; ++j) lc[j] = (v2f){0.f, 0.f};

    const float4* kp = kv + ((size_t)(b * N_ + k0)) * H_ + t;

    #pragma unroll 4
    for (int k = 0; k < N_ / KC; ++k) {
        float4 v = kp[(size_t)k * H_];            // {Et, M, Mh, 0}
        v2f mm = (v2f){v.y, v.z};
        #pragma unroll
        for (int j = 0; j < QQ / 2; ++j) {
            v2f e2 = eta2[j] * v.x;                         // v_pk_mul_f32
            v2f a2 = e2 * (v2f)(LOG2E) + (v2f)(-LOG2E);     // v_pk_fma_f32
            float pn0 = __builtin_amdgcn_exp2f(a2.x);
            float pn1 = __builtin_amdgcn_exp2f(a2.y);
            float p0 = (e2.x > 1.f) ? e2.x : pn0;
            float p1 = (e2.y > 1.f) ? e2.y : pn1;
            lc[2 * j]     += (v2f){p0, p0} * mm;            // v_pk_fma_f32
            lc[2 * j + 1] += (v2f){p1, p1} * mm;            // v_pk_fma_f32
        }
    }

    #pragma unroll
    for (int j = 0; j < QQ; ++j) {
        accum[((size_t)c * (B_ * N_) + b * N_ + q0 + j) * H_ + t] =
            make_float2(lc[j].x, lc[j].y);
    }

    // ---- fan-in: last block of this (b,qg) group finalizes ----
    __threadfence();                      // make partial writes visible
    __shared__ unsigned int last;
    __syncthreads();
    if (t == 0) {
        const int g = b * (N_ / QQ) + qg;
        last = atomicAdd(&cnt[g], 1u);
    }
    __syncthreads();
    if (last == KC - 1) {
        __threadfence();                  // acquire other blocks' writes
        #pragma unroll
        for (int j = 0; j < QQ; ++j) {
            const size_t o = ((size_t)(b * N_ + q0 + j)) * H_ + t;
            float L = 0.f, C = 0.f;
            #pragma unroll
            for (int cc2 = 0; cc2 < KC; ++cc2) {
                float2 a = accum[(size_t)cc2 * (B_ * N_ * H_) + o];
                L += a.x;
                C += a.y;
            }
            out[o] = C / L;
        }
    }
}

extern "C" void kernel_launch(void* const* d_in, const int* in_sizes, int n_in,
                              void* d_out, int out_size, void* d_ws, size_t ws_size,
                              hipStream_t stream) {
    const float* word_vecs = (const float*)d_in[0];
    const float* mask      = (const float*)d_in[1];
    const float* Wx_w      = (const float*)d_in[2];
    const float* Wx_b      = (const float*)d_in[3];
    const float* Wa_w      = (const float*)d_in[4];
    const float* Wa_b      = (const float*)d_in[5];
    const float* Ua_w      = (const float*)d_in[6];
    const float* Ua_b      = (const float*)d_in[7];
    float* out = (float*)d_out;

    // workspace layout (16B aligned): ~38.6 MB
    char* p = (char*)d_ws;
    float*  WxT4  = (float*)p;   p += (size_t)75 * 512 * 4;
    float*  WaT4  = (float*)p;   p += (size_t)32 * 512 * 4;
    float*  UaT4  = (float*)p;   p += (size_t)32 * 512 * 4;
    float*  Eta   = (float*)p;   p += (size_t)B_ * N_ * H_ * 4;
    float4* kv    = (float4*)p;  p += (size_t)B_ * N_ * H_ * 16;
    float2* accum = (float2*)p;  p += (size_t)KC * B_ * N_ * H_ * 8;
    unsigned int* cnt = (unsigned int*)p;  p += 256 * sizeof(unsigned int);

    pack_all<<<IND_ + 2 * H_, 128, 0, stream>>>(Wx_w, Wa_w, Ua_w,
                                                WxT4, WaT4, UaT4, cnt);

    prep4<<<(B_ * N_) / RR, 128, 0, stream>>>(word_vecs, WxT4, Wx_b,
                                              WaT4, Wa_b, UaT4, Ua_b,
                                              mask, Eta, kv);

    dim3 grid(KC, N_ / QQ, B_);
    attn5<<<grid, 128, 0, stream>>>(Eta, kv, accum, cnt, out);
}

// Round 8
// 132.084 us; speedup vs baseline: 3.4235x; 3.4235x over previous
//
#include <hip/hip_runtime.h>

#define B_    4
#define N_    512
#define IND_  300
#define H_    128
#define QQ    8          // queries per attention block
#define KC    8          // k-chunks (16 MB accum; KC=16 measured worse - R4)
#define RR    4          // rows per prep block
#define LOG2E 1.4426950408889634f

typedef float v2f __attribute__((ext_vector_type(2)));

// ---------------------------------------------------------------------------
// Packing: transpose weights to [i/4][t][4] float4 tiles (coalesced dwordx4
// in prep). Wa/Ua pre-scaled by log2e so downstream uses raw exp2.
// ---------------------------------------------------------------------------
__global__ void pack_all(const float* __restrict__ Wx_w,
                         const float* __restrict__ Wa_w,
                         const float* __restrict__ Ua_w,
                         float* __restrict__ WxT4,
                         float* __restrict__ WaT4,
                         float* __restrict__ UaT4) {
    const int blk = blockIdx.x;
    const int t   = threadIdx.x;
    if (blk < IND_) {
        const int i = blk;
        WxT4[(i >> 2) * 512 + t * 4 + (i & 3)] = Wx_w[t * IND_ + i];
    } else if (blk < IND_ + H_) {
        const int i = blk - IND_;
        WaT4[(i >> 2) * 512 + t * 4 + (i & 3)] = Wa_w[t * H_ + i] * LOG2E;
    } else {
        const int i = blk - IND_ - H_;
        UaT4[(i >> 2) * 512 + t * 4 + (i & 3)] = Ua_w[t * H_ + i] * LOG2E;
    }
}

// ---------------------------------------------------------------------------
// Prep, RR rows per block: h = tanh(x.Wx^T + bx)
//   Eta = exp(h.Wa^T + ba)                         [B*N, H]
//   kv  = {Et=exp(h.Ua^T+bu), M=exp(mask), M*h, 0} [B*N, H]
// Weight loads coalesced dwordx4, amortized over RR rows; x/h staged in LDS.
// ---------------------------------------------------------------------------
__global__ __launch_bounds__(128) void prep4(
    const float* __restrict__ x,      // [B*N, IND]
    const float* __restrict__ WxT4,   // [75][128][4]
    const float* __restrict__ Wx_b,
    const float* __restrict__ WaT4,   // [32][128][4], pre-scaled log2e
    const float* __restrict__ Wa_b,
    const float* __restrict__ UaT4,   // [32][128][4], pre-scaled log2e
    const float* __restrict__ Ua_b,
    const float* __restrict__ mask,   // [B*N, H]
    float* __restrict__ Eta,          // [B*N, H]
    float4* __restrict__ kv)          // [B*N, H]
{
    __shared__ __align__(16) float xs[RR * IND_];
    __shared__ __align__(16) float hs[RR][H_];

    const int r0 = blockIdx.x * RR;
    const int t  = threadIdx.x;

    const float4* xg = (const float4*)(x + (size_t)r0 * IND_);
    float4* xs4 = (float4*)xs;
    #pragma unroll
    for (int i = t; i < RR * IND_ / 4; i += 128) xs4[i] = xg[i];
    __syncthreads();

    float acc[RR];
    {
        const float bx = Wx_b[t];
        #pragma unroll
        for (int r = 0; r < RR; ++r) acc[r] = bx;
    }
    const float4* w4 = (const float4*)WxT4 + t;
    #pragma unroll 5
    for (int i4 = 0; i4 < IND_ / 4; ++i4) {
        float4 w = w4[i4 * 128];
        #pragma unroll
        for (int r = 0; r < RR; ++r) {
            float4 xv = *(const float4*)(xs + r * IND_ + 4 * i4);
            acc[r] = fmaf(w.x, xv.x, acc[r]);
            acc[r] = fmaf(w.y, xv.y, acc[r]);
            acc[r] = fmaf(w.z, xv.z, acc[r]);
            acc[r] = fmaf(w.w, xv.w, acc[r]);
        }
    }
    #pragma unroll
    for (int r = 0; r < RR; ++r) hs[r][t] = tanhf(acc[r]);
    __syncthreads();

    float accA[RR], accU[RR];
    {
        const float ba = Wa_b[t] * LOG2E;
        const float bu = Ua_b[t] * LOG2E;
        #pragma unroll
        for (int r = 0; r < RR; ++r) { accA[r] = ba; accU[r] = bu; }
    }
    const float4* wa4 = (const float4*)WaT4 + t;
    const float4* ua4 = (const float4*)UaT4 + t;
    #pragma unroll 4
    for (int i4 = 0; i4 < H_ / 4; ++i4) {
        float4 wa = wa4[i4 * 128];
        float4 ua = ua4[i4 * 128];
        #pragma unroll
        for (int r = 0; r < RR; ++r) {
            float4 hv = *(const float4*)(&hs[r][4 * i4]);
            accA[r] = fmaf(wa.x, hv.x, accA[r]);
            accA[r] = fmaf(wa.y, hv.y, accA[r]);
            accA[r] = fmaf(wa.z, hv.z, accA[r]);
            accA[r] = fmaf(wa.w, hv.w, accA[r]);
            accU[r] = fmaf(ua.x, hv.x, accU[r]);
            accU[r] = fmaf(ua.y, hv.y, accU[r]);
            accU[r] = fmaf(ua.z, hv.z, accU[r]);
            accU[r] = fmaf(ua.w, hv.w, accU[r]);
        }
    }
    #pragma unroll
    for (int r = 0; r < RR; ++r) {
        const size_t o = (size_t)(r0 + r) * H_ + t;
        Eta[o]  = __builtin_amdgcn_exp2f(accA[r]);
        float M = __builtin_amdgcn_exp2f(mask[o] * LOG2E);
        float h = hs[r][t];
        kv[o]   = make_float4(__builtin_amdgcn_exp2f(accU[r]), M, M * h, 0.f);
    }
}

// ---------------------------------------------------------------------------
// Attention, ~5 issue slots + 1 trans per score:
//   e  = Eta*Et                      (pk_mul, 2 scores/inst)
//   a  = e*log2e - log2e             (pk_fma)
//   p0 = (e > 1) ? e : exp2(a)       (cmp + cndmask — select is irreducible:
//                                     for e>1 we need the SMALLER of the
//                                     pair, for e<1 the LARGER, so no
//                                     min/max identity exists; R7's min()
//                                     silently dropped the elu neg branch)
//   l += p0*M ; c += p0*Mh           (one pk_fma per score)
// ---------------------------------------------------------------------------
__global__ __launch_bounds__(128) void attn6(
    const float* __restrict__ Eta,    // [B*N, H]
    const float4* __restrict__ kv,    // [B*N, H] {Et, M, Mh, 0}
    float2* __restrict__ accum)       // [KC, B*N, H] {l, c}
{
    const int c  = blockIdx.x;        // 0..KC-1
    const int qg = blockIdx.y;        // 0..N/QQ-1
    const int b  = blockIdx.z;        // 0..B-1
    const int t  = threadIdx.x;
    const int q0 = qg * QQ;
    const int k0 = c * (N_ / KC);

    v2f eta2[QQ / 2];
    v2f lc[QQ];                       // {l, c} per q
    #pragma unroll
    for (int j = 0; j < QQ / 2; ++j) {
        eta2[j].x = Eta[((size_t)(b * N_ + q0 + 2 * j)) * H_ + t];
        eta2[j].y = Eta[((size_t)(b * N_ + q0 + 2 * j + 1)) * H_ + t];
    }
    #pragma unroll
    for (int j = 0; j < QQ; ++j) lc[j] = (v2f){0.f, 0.f};

    const float4* kp = kv + ((size_t)(b * N_ + k0)) * H_ + t;

    #pragma unroll 4
    for (int k = 0; k < N_ / KC; ++k) {
        float4 v = kp[(size_t)k * H_];            // {Et, M, Mh, 0}
        v2f mm = (v2f){v.y, v.z};
        #pragma unroll
        for (int j = 0; j < QQ / 2; ++j) {
            v2f e2 = eta2[j] * v.x;                         // v_pk_mul_f32
            v2f a2 = e2 * (v2f)(LOG2E) + (v2f)(-LOG2E);     // v_pk_fma_f32
            float pn0 = __builtin_amdgcn_exp2f(a2.x);
            float pn1 = __builtin_amdgcn_exp2f(a2.y);
            float p0 = (e2.x > 1.f) ? e2.x : pn0;           // cmp+cndmask
            float p1 = (e2.y > 1.f) ? e2.y : pn1;
            lc[2 * j]     += (v2f){p0, p0} * mm;            // v_pk_fma_f32
            lc[2 * j + 1] += (v2f){p1, p1} * mm;            // v_pk_fma_f32
        }
    }

    #pragma unroll
    for (int j = 0; j < QQ; ++j) {
        accum[((size_t)c * (B_ * N_) + b * N_ + q0 + j) * H_ + t] =
            make_float2(lc[j].x, lc[j].y);
    }
}

__global__ void fin6(const float2* __restrict__ accum, float* __restrict__ out) {
    const int idx = blockIdx.x * 256 + threadIdx.x;   // B*N*H threads
    float L = 0.f, C = 0.f;
    #pragma unroll
    for (int c = 0; c < KC; ++c) {
        float2 a = accum[(size_t)c * (B_ * N_ * H_) + idx];
        L += a.x;
        C += a.y;
    }
    out[idx] = C / L;
}

extern "C" void kernel_launch(void* const* d_in, const int* in_sizes, int n_in,
                              void* d_out, int out_size, void* d_ws, size_t ws_size,
                              hipStream_t stream) {
    const float* word_vecs = (const float*)d_in[0];
    const float* mask      = (const float*)d_in[1];
    const float* Wx_w      = (const float*)d_in[2];
    const float* Wx_b      = (const float*)d_in[3];
    const float* Wa_w      = (const float*)d_in[4];
    const float* Wa_b      = (const float*)d_in[5];
    const float* Ua_w      = (const float*)d_in[6];
    const float* Ua_b      = (const float*)d_in[7];
    float* out = (float*)d_out;

    // workspace layout (16B aligned): ~21.3 MB
    char* p = (char*)d_ws;
    float*  WxT4  = (float*)p;   p += (size_t)75 * 512 * 4;
    float*  WaT4  = (float*)p;   p += (size_t)32 * 512 * 4;
    float*  UaT4  = (float*)p;   p += (size_t)32 * 512 * 4;
    float*  Eta   = (float*)p;   p += (size_t)B_ * N_ * H_ * 4;
    float4* kv    = (float4*)p;  p += (size_t)B_ * N_ * H_ * 16;
    float2* accum = (float2*)p;  p += (size_t)KC * B_ * N_ * H_ * 8;

    pack_all<<<IND_ + 2 * H_, 128, 0, stream>>>(Wx_w, Wa_w, Ua_w,
                                                WxT4, WaT4, UaT4);

    prep4<<<(B_ * N_) / RR, 128, 0, stream>>>(word_vecs, WxT4, Wx_b,
                                              WaT4, Wa_b, UaT4, Ua_b,
                                              mask, Eta, kv);

    dim3 grid(KC, N_ / QQ, B_);
    attn6<<<grid, 128, 0, stream>>>(Eta, kv, accum);

    fin6<<<(B_ * N_ * H_) / 256, 256, 0, stream>>>(accum, out);
}